// Round 5
// baseline (7674.535 us; speedup 1.0000x reference)
//
#include <hip/hip_runtime.h>
#include <cmath>

#define NB 32
#define NS 1024
#define NI 128
#define NH 1024
#define NO 64

typedef float f32x4 __attribute__((ext_vector_type(4)));
typedef float f32x2 __attribute__((ext_vector_type(2)));

// Persistent ESN: 256 blocks x 256 threads.
//   blockIdx & 7  -> batch group bg (4 batches, float4-interleaved)
//   blockIdx >> 3 -> row slice rs (32 rows of h), output cols [2rs, 2rs+2)
// Exchange through LLC (sc0 sc1 = bypass L1+L2, device-coherent point):
//   producers: 32x dwordx4 stores -> vmcnt(0) -> syncthreads -> flag store
//   consumers: poll per-producer flag (coalesced 8 flags/wave) -> dwordx4 loads
// No atomic-RMW fan-in (round-3 residual), no cache flush/inv (round-1 killer).

__device__ __forceinline__ void store_llc4(f32x4* p, f32x4 v) {
    asm volatile("global_store_dwordx4 %0, %1, off sc0 sc1" :: "v"(p), "v"(v) : "memory");
}
__device__ __forceinline__ f32x4 load_llc4(const f32x4* p) {
    f32x4 v;
    asm volatile("global_load_dwordx4 %0, %1, off sc0 sc1" : "=v"(v) : "v"(p));
    return v;   // NOT valid until s_waitcnt vmcnt(0) + sched_barrier
}
__device__ __forceinline__ void store_llc_u32(unsigned* p, unsigned v) {
    asm volatile("global_store_dword %0, %1, off sc0 sc1" :: "v"(p), "v"(v) : "memory");
}
__device__ __forceinline__ unsigned poll_llc_u32(const unsigned* p) {
    unsigned v;
    asm volatile("global_load_dword %0, %1, off sc0 sc1\n\ts_waitcnt vmcnt(0)"
                 : "=v"(v) : "v"(p) : "memory");
    return v;
}

extern "C" __global__ void __launch_bounds__(256, 1)
esn_persistent(const float* __restrict__ x,
               const float* __restrict__ W_res,
               const float* __restrict__ W_in,
               const float* __restrict__ W_out_w,
               const float* __restrict__ W_out_b,
               float* __restrict__ out,
               unsigned char* ws)
{
    const int tid  = threadIdx.x;
    const int lane = tid & 63;
    const int wv   = tid >> 6;
    const int bg   = (int)blockIdx.x & 7;
    const int rs   = (int)blockIdx.x >> 3;
    const int rt   = tid & 7;    // row tile (4 rows) within slice
    const int kid  = tid >> 3;   // k-chunk [kid*32, kid*32+32)  == slice id
    const int r0   = rs * 32 + rt * 4;
    const int k0   = kid * 32;
    const int o0   = rs * 2;
    const int p    = tid >> 3;   // reload: slice owned by this thread
    const int q    = tid & 7;    // reload: quad of rows within slice

    unsigned* flags = (unsigned*)ws;             // [8 bg][32 p] stride-2 uints (2KB)
    f32x4* h_buf4   = (f32x4*)(ws + 4096);       // [2][8 bg][1024 r] float4 over bb

    __shared__ f32x4 h4[1055];       // h (4 batches), padded slot(r)=r+(r>>5)
    __shared__ f32x4 xl4[128];       // x_s (4 batches) [bb*32 + i/4]
    __shared__ f32x4 redA[128];      // [wv][rt][rr] -> float4 over bb
    __shared__ float red2[4][8][2][4];

    // ---- one-time register loads ----
    float w_r[4][32];                // W_res[r0+rr][k0+kk]
#pragma unroll
    for (int rr = 0; rr < 4; ++rr) {
        const float* wp = W_res + (r0 + rr) * NH + k0;
#pragma unroll
        for (int qq = 0; qq < 8; ++qq) {
            f32x4 v = *(const f32x4*)(wp + qq * 4);
            w_r[rr][qq * 4 + 0] = v.x;
            w_r[rr][qq * 4 + 1] = v.y;
            w_r[rr][qq * 4 + 2] = v.z;
            w_r[rr][qq * 4 + 3] = v.w;
        }
    }
    f32x4 w_i[4];                    // W_in[r0+rr][kid*4 .. +4)
#pragma unroll
    for (int rr = 0; rr < 4; ++rr)
        w_i[rr] = *(const f32x4*)(W_in + (r0 + rr) * NI + kid * 4);
    float w_o[2][4];                 // W_out_w[o0+o][p*32+q*4+j]
#pragma unroll
    for (int j = 0; j < 4; ++j) {
        const int hr = p * 32 + q * 4 + j;
        w_o[0][j] = W_out_w[(o0 + 0) * NH + hr];
        w_o[1][j] = W_out_w[(o0 + 1) * NH + hr];
    }
    const float bias = W_out_b[o0 + ((tid >> 2) & 1)];

    const float* xrow = x + ((bg * 4 + wv) * NS) * NI + lane * 2;
    float* outb = out + (bg * 4) * (NS * NO);

    f32x2 xstash = *(const f32x2*)(xrow);   // prefetch x_0

    for (int s = 0; s < NS; ++s) {
        // stage x_s from the prefetch register
        ((f32x2*)xl4)[wv * 64 + lane] = xstash;
        __syncthreads();                                   // A
        {   // prefetch x_{s+1}; completes under compute phase
            int sn = (s + 1 < NS) ? s + 1 : s;
            xstash = *(const f32x2*)(xrow + sn * NI);
        }

        float acc[4][4];
#pragma unroll
        for (int rr = 0; rr < 4; ++rr)
#pragma unroll
            for (int bb = 0; bb < 4; ++bb) acc[rr][bb] = 0.f;

        {   // u = W_in . x_s   (i-range [kid*4, kid*4+4))
            f32x4 xv[4];
#pragma unroll
            for (int bb = 0; bb < 4; ++bb) xv[bb] = xl4[bb * 32 + kid];
#pragma unroll
            for (int rr = 0; rr < 4; ++rr) {
#pragma unroll
                for (int bb = 0; bb < 4; ++bb) {
                    float v = acc[rr][bb];
                    v = fmaf(w_i[rr].x, xv[bb].x, v);
                    v = fmaf(w_i[rr].y, xv[bb].y, v);
                    v = fmaf(w_i[rr].z, xv[bb].z, v);
                    v = fmaf(w_i[rr].w, xv[bb].w, v);
                    acc[rr][bb] = v;
                }
            }
        }
        if (s != 0) {   // W_res . h_{s-1}  (k-range [k0, k0+32))
            const f32x4* hp = &h4[k0 + kid];   // padded base; imm offsets below
#pragma unroll
            for (int kk = 0; kk < 32; ++kk) {
                f32x4 hv = hp[kk];
#pragma unroll
                for (int rr = 0; rr < 4; ++rr) {
                    float w = w_r[rr][kk];
                    acc[rr][0] = fmaf(w, hv.x, acc[rr][0]);
                    acc[rr][1] = fmaf(w, hv.y, acc[rr][1]);
                    acc[rr][2] = fmaf(w, hv.z, acc[rr][2]);
                    acc[rr][3] = fmaf(w, hv.w, acc[rr][3]);
                }
            }
        }
        // reduce over kid: in-wave (lane bits 3..5), cross-wave via LDS
#pragma unroll
        for (int rr = 0; rr < 4; ++rr)
#pragma unroll
            for (int bb = 0; bb < 4; ++bb) {
                float v = acc[rr][bb];
                v += __shfl_xor(v, 8, 64);
                v += __shfl_xor(v, 16, 64);
                v += __shfl_xor(v, 32, 64);
                acc[rr][bb] = v;
            }
        if ((lane & 56) == 0) {
#pragma unroll
            for (int rr = 0; rr < 4; ++rr) {
                f32x4 t = {acc[rr][0], acc[rr][1], acc[rr][2], acc[rr][3]};
                redA[(wv * 8 + rt) * 4 + rr] = t;
            }
        }
        __syncthreads();                                   // B
        const int hsel = s & 1;
        f32x4* hb4s = h_buf4 + hsel * 8192 + bg * 1024 + rs * 32;
        if (tid < 32) {    // gather row rl=tid across k-parts, tanh, 16B store
            const int rt2 = tid >> 2, rr2 = tid & 3;
            f32x4 v = redA[(0 * 8 + rt2) * 4 + rr2] + redA[(1 * 8 + rt2) * 4 + rr2]
                    + redA[(2 * 8 + rt2) * 4 + rr2] + redA[(3 * 8 + rt2) * 4 + rr2];
            v.x = tanhf(v.x); v.y = tanhf(v.y); v.z = tanhf(v.z); v.w = tanhf(v.w);
            store_llc4(hb4s + tid, v);
            asm volatile("s_waitcnt vmcnt(0)" ::: "memory");   // own stores ack'd
        }
        __syncthreads();                                   // B2
        if (tid == 0) store_llc_u32(flags + (bg * 32 + rs) * 2, (unsigned)(s + 1));

        // ---- poll per-producer flag, then vector-reload slice p ----
        {
            const unsigned tgt = (unsigned)(s + 1);
            const unsigned* fp = flags + (bg * 32 + p) * 2;
            while (poll_llc_u32(fp) < tgt) {}
        }
        __builtin_amdgcn_sched_barrier(0);
        const f32x4* hb4 = h_buf4 + hsel * 8192 + bg * 1024 + p * 32 + q * 4;
        f32x4 hv0 = load_llc4(hb4 + 0);
        f32x4 hv1 = load_llc4(hb4 + 1);
        f32x4 hv2 = load_llc4(hb4 + 2);
        f32x4 hv3 = load_llc4(hb4 + 3);
        asm volatile("s_waitcnt vmcnt(0)" ::: "memory");
        __builtin_amdgcn_sched_barrier(0);

        {   // LDS stage, padded: row r in [p*32+q*4, +4) -> slot r + p
            const int base = p * 33 + q * 4;
            h4[base + 0] = hv0; h4[base + 1] = hv1;
            h4[base + 2] = hv2; h4[base + 3] = hv3;
        }
        // readout partials on the 4 rows this thread just loaded
        float ro[2][4];
#pragma unroll
        for (int o = 0; o < 2; ++o) {
            ro[o][0] = fmaf(w_o[o][0], hv0.x, fmaf(w_o[o][1], hv1.x,
                       fmaf(w_o[o][2], hv2.x, w_o[o][3] * hv3.x)));
            ro[o][1] = fmaf(w_o[o][0], hv0.y, fmaf(w_o[o][1], hv1.y,
                       fmaf(w_o[o][2], hv2.y, w_o[o][3] * hv3.y)));
            ro[o][2] = fmaf(w_o[o][0], hv0.z, fmaf(w_o[o][1], hv1.z,
                       fmaf(w_o[o][2], hv2.z, w_o[o][3] * hv3.z)));
            ro[o][3] = fmaf(w_o[o][0], hv0.w, fmaf(w_o[o][1], hv1.w,
                       fmaf(w_o[o][2], hv2.w, w_o[o][3] * hv3.w)));
        }
#pragma unroll
        for (int o = 0; o < 2; ++o)
#pragma unroll
            for (int bb = 0; bb < 4; ++bb) {
                float v = ro[o][bb];
                v += __shfl_xor(v, 1, 64);
                v += __shfl_xor(v, 2, 64);
                v += __shfl_xor(v, 4, 64);
                ro[o][bb] = v;
            }
        if ((lane & 7) == 0) {
#pragma unroll
            for (int o = 0; o < 2; ++o)
#pragma unroll
                for (int bb = 0; bb < 4; ++bb)
                    red2[wv][lane >> 3][o][bb] = ro[o][bb];
        }
        __syncthreads();                                   // DE (h4 + red2 ready)
        if (tid < 8) {
            const int o  = tid >> 2;
            const int bb = tid & 3;
            float v = bias;
#pragma unroll
            for (int ww = 0; ww < 4; ++ww)
#pragma unroll
                for (int g = 0; g < 8; ++g)
                    v += red2[ww][g][o][bb];
            outb[bb * (NS * NO) + s * NO + o0 + o] = v;
        }
    }
}

extern "C" void kernel_launch(void* const* d_in, const int* in_sizes, int n_in,
                              void* d_out, int out_size, void* d_ws, size_t ws_size,
                              hipStream_t stream)
{
    const float* x       = (const float*)d_in[0];
    const float* W_res   = (const float*)d_in[1];
    const float* W_in    = (const float*)d_in[2];
    const float* W_out_w = (const float*)d_in[3];
    const float* W_out_b = (const float*)d_in[4];
    float* out           = (float*)d_out;
    unsigned char* ws    = (unsigned char*)d_ws;

    hipMemsetAsync(d_ws, 0, 4096, stream);   // zero flag region each call

    void* args[] = {&x, &W_res, &W_in, &W_out_w, &W_out_b, &out, &ws};
    hipError_t err = hipLaunchCooperativeKernel((void*)esn_persistent,
                                                dim3(256), dim3(256),
                                                args, 0, stream);
    if (err != hipSuccess) {
        (void)hipGetLastError();
        // fallback: plain launch (1 small block per CU -> co-resident in practice)
        hipLaunchKernelGGL(esn_persistent, dim3(256), dim3(256), 0, stream,
                           x, W_res, W_in, W_out_w, W_out_b, out, ws);
    }
}